// Round 10
// baseline (216.579 us; speedup 1.0000x reference)
//
#include <hip/hip_runtime.h>
#include <math.h>

// Gen2AssocModel forward. T=512, B=64, N=32, HID=1024, SEQ_WIDTH=64.
// 4 dispatches (launch/fixed-cost dominated regime):
//   prep:    W1eff = W_in @ [Wk1|Wv1|Wq1] (65x96), b1eff, const2; zero ctrl.
//   kvq1p1c: per (b,seg): GEMM tile -> LDS -> kvq1 global; phase1 (linear
//            prefix S, max|p| P) from LDS; block (maxS,maxP) -> atomicMax;
//            LAST block per b (atomic counter) runs cert test; clean ->
//            rowany1=0; dirty -> EXACT serial replay -> dmask1+rowany1.
//            Cert: ub = maxP + maxS*1.0012 (chain bound S/(1-0.9^64)),
//            1e-3 margin >> fp reassoc error; conservative => exact.
//   midc:    per (b,seg): clean -> just counter; mixed -> exact dirty rows ->
//            kvq2 + tile phase1 -> atomicMax; last block per b: cert with
//            closed-form scs=max|c2k|*max|c2v|*G64 for clean segs; dirty ->
//            replay with const2-row substitution -> dmask2+rowany2.
//   out:     rowany2 fast path -> sigmoid(b_out); sparse cold exact.
// Workspace ~32 MB.

#define T_STEPS 512
#define BATCH   64
#define NN      32
#define HID     1024
#define INW     65
#define OUTW    64
#define KVQ     96

__device__ __forceinline__ float sigmoidf_(float x) { return 1.0f / (1.0f + expf(-x)); }

// ---------------------------------------------------------------- prep
__global__ __launch_bounds__(512) void prep_kernel(
    const float* __restrict__ W_in, const float* __restrict__ b_in,
    const float* __restrict__ Wk1, const float* __restrict__ bk1,
    const float* __restrict__ Wv1, const float* __restrict__ bv1,
    const float* __restrict__ Wq1, const float* __restrict__ bq1,
    const float* __restrict__ b_mid,
    const float* __restrict__ Wk2, const float* __restrict__ bk2,
    const float* __restrict__ Wv2, const float* __restrict__ bv2,
    const float* __restrict__ Wq2, const float* __restrict__ bq2,
    float* __restrict__ W1eff, float* __restrict__ b1eff,
    float* __restrict__ const2, unsigned int* __restrict__ ctrl)
{
    const int m = blockIdx.x;                 // 0..66
    const int tid = threadIdx.x;
    if (m == 0 && tid < 384) ctrl[tid] = 0u;  // cnt1[64] cnt2[64] amax1[128] amax2[128]
    __shared__ float srcv[HID];
    __shared__ float part[512];
    for (int h = tid; h < HID; h += 512) {
        float s;
        if (m < INW)       s = W_in[m * HID + h];
        else if (m == INW) s = b_in[h];
        else               s = fmaxf(b_mid[h], 0.f);
        srcv[h] = s;
    }
    __syncthreads();
    const int hq = tid >> 7, ns = tid & 127;  // ns<96 active
    const int sel = ns >> 5, nn = ns & 31;
    const bool layer2 = (m == INW + 1);
    const float* W = layer2 ? (sel == 0 ? Wk2 : sel == 1 ? Wv2 : Wq2)
                            : (sel == 0 ? Wk1 : sel == 1 ? Wv1 : Wq1);
    float acc = 0.f;
    if (ns < KVQ) {
        const int h0 = hq * 256;
        #pragma unroll 8
        for (int hh = 0; hh < 256; ++hh)
            acc = fmaf(srcv[h0 + hh], W[(h0 + hh) * NN + nn], acc);
    }
    part[tid] = acc;
    __syncthreads();
    if (hq == 0 && ns < KVQ) {
        float tot = part[ns] + part[128 + ns] + part[256 + ns] + part[384 + ns];
        if (m < INW) {
            W1eff[m * KVQ + ns] = tot;
        } else if (m == INW) {
            tot += (sel == 0 ? bk1 : sel == 1 ? bv1 : bq1)[nn];
            b1eff[ns] = tot;
        } else {
            tot += (sel == 0 ? bk2 : sel == 1 ? bv2 : bq2)[nn];
            const2[ns] = (sel == 2) ? sigmoidf_(tot) : tot;
        }
    }
}

// ---------------------------------------------------------------- kvq1 + phase1 + cert/cleanup
// grid 512 = b*8+seg, block 256 (4 waves), ~51 KB LDS -> 3 blocks/CU.
__global__ __launch_bounds__(256) void kvq1p1c_kernel(
    const float* __restrict__ x, const float* __restrict__ W1eff,
    const float* __restrict__ b1eff, float* __restrict__ kvq1,
    unsigned int* __restrict__ rowany1, unsigned int* __restrict__ dmask1,
    unsigned int* __restrict__ cnt1, float* __restrict__ amax1)
{
    const int b = blockIdx.x >> 3, seg = blockIdx.x & 7;
    const int tid = threadIdx.x;
    __shared__ __align__(16) float Ws[INW * KVQ];   // 24.4 KB
    __shared__ __align__(16) float bs[KVQ];
    __shared__ __align__(16) float pool[64 * 100];  // 25.6 KB: xsT -> kt -> buf
    __shared__ float red[8];
    __shared__ unsigned int lastf, dirtyf;
    for (int i4 = tid; i4 < (INW * KVQ) / 4; i4 += 256)
        ((float4*)Ws)[i4] = ((const float4*)W1eff)[i4];
    if (tid < KVQ) bs[tid] = b1eff[tid];
    // xsT[m*68 + r] = x[((seg*64+r)*64 + b)*65 + m]
    for (int l = tid; l < 64 * INW; l += 256) {
        const int r = l / INW, m = l - r * INW;
        pool[m * 68 + r] = x[((size_t)((seg * 64 + r) * 64 + b)) * INW + m];
    }
    __syncthreads();
    // ---- GEMM: 2 rows x 12 cols per thread ----
    const int rg = tid >> 3;          // 0..31 -> rows rg*2, rg*2+1
    const int c0 = (tid & 7) * 12;
    float acc[2][12];
    #pragma unroll
    for (int r = 0; r < 2; ++r)
        #pragma unroll
        for (int k = 0; k < 12; ++k) acc[r][k] = bs[c0 + k];
    #pragma unroll 5
    for (int m = 0; m < INW; ++m) {
        const float2 xv = *(const float2*)&pool[m * 68 + rg * 2];
        const float4 w0 = *(const float4*)&Ws[m * KVQ + c0];
        const float4 w1 = *(const float4*)&Ws[m * KVQ + c0 + 4];
        const float4 w2 = *(const float4*)&Ws[m * KVQ + c0 + 8];
        const float xr[2] = {xv.x, xv.y};
        const float wk[12] = {w0.x, w0.y, w0.z, w0.w, w1.x, w1.y, w1.z, w1.w,
                              w2.x, w2.y, w2.z, w2.w};
        #pragma unroll
        for (int r = 0; r < 2; ++r)
            #pragma unroll
            for (int k = 0; k < 12; ++k)
                acc[r][k] = fmaf(xr[r], wk[k], acc[r][k]);
    }
    __syncthreads();   // xsT dead; pool becomes kt[row*100 + col]
    #pragma unroll
    for (int r = 0; r < 2; ++r) {
        const int row = rg * 2 + r;
        float v[12];
        #pragma unroll
        for (int k = 0; k < 12; ++k)
            v[k] = (c0 + k >= 2 * NN) ? sigmoidf_(acc[r][k]) : acc[r][k];
        float* kt = &pool[row * 100 + c0];
        *(float4*)&kt[0] = make_float4(v[0], v[1], v[2], v[3]);
        *(float4*)&kt[4] = make_float4(v[4], v[5], v[6], v[7]);
        *(float4*)&kt[8] = make_float4(v[8], v[9], v[10], v[11]);
        float* o = kvq1 + ((size_t)b * T_STEPS + seg * 64 + row) * KVQ + c0;
        *(float4*)&o[0] = make_float4(v[0], v[1], v[2], v[3]);
        *(float4*)&o[4] = make_float4(v[4], v[5], v[6], v[7]);
        *(float4*)&o[8] = make_float4(v[8], v[9], v[10], v[11]);
    }
    __syncthreads();
    // ---- phase1 from LDS tile: 4 membranes/thread, register dbuf x4 steps ----
    const int i0 = (tid >> 5) * 4, j = tid & 31;
    float p[4] = {0.f, 0.f, 0.f, 0.f};
    float am[4] = {0.f, 0.f, 0.f, 0.f};
    float4 kb[2]; float vb[2][4]; float4 kt4[2][4];
    (void)kb;
    #pragma unroll
    for (int d = 0; d < 4; ++d) {
        kt4[0][d] = *(const float4*)&pool[d * 100 + i0];
        vb[0][d] = pool[d * 100 + 32 + j];
    }
    #pragma unroll
    for (int bt = 0; bt < 16; ++bt) {
        const int cb = bt & 1;
        if (bt < 15) {
            #pragma unroll
            for (int d = 0; d < 4; ++d) {
                const int dt = (bt + 1) * 4 + d;
                kt4[cb ^ 1][d] = *(const float4*)&pool[dt * 100 + i0];
                vb[cb ^ 1][d] = pool[dt * 100 + 32 + j];
            }
        }
        #pragma unroll
        for (int d = 0; d < 4; ++d) {
            const float vv = vb[cb][d];
            p[0] = fmaf(0.9f, p[0], kt4[cb][d].x * vv); am[0] = fmaxf(am[0], fabsf(p[0]));
            p[1] = fmaf(0.9f, p[1], kt4[cb][d].y * vv); am[1] = fmaxf(am[1], fabsf(p[1]));
            p[2] = fmaf(0.9f, p[2], kt4[cb][d].z * vv); am[2] = fmaxf(am[2], fabsf(p[2]));
            p[3] = fmaf(0.9f, p[3], kt4[cb][d].w * vv); am[3] = fmaxf(am[3], fabsf(p[3]));
        }
    }
    float ls = 0.f, lp = 0.f;
    #pragma unroll
    for (int r = 0; r < 4; ++r) { ls = fmaxf(ls, fabsf(p[r])); lp = fmaxf(lp, am[r]); }
    #pragma unroll
    for (int off = 32; off; off >>= 1) {
        ls = fmaxf(ls, __shfl_xor(ls, off));
        lp = fmaxf(lp, __shfl_xor(lp, off));
    }
    if ((tid & 63) == 0) { red[(tid >> 6) * 2] = ls; red[(tid >> 6) * 2 + 1] = lp; }
    __syncthreads();
    if (tid == 0) {
        const float bS = fmaxf(fmaxf(red[0], red[2]), fmaxf(red[4], red[6]));
        const float bP = fmaxf(fmaxf(red[1], red[3]), fmaxf(red[5], red[7]));
        atomicMax((int*)&amax1[b * 2 + 0], __float_as_int(bS));   // vals >= 0
        atomicMax((int*)&amax1[b * 2 + 1], __float_as_int(bP));
    }
    // ---- last-block handoff ----
    __threadfence();
    __syncthreads();
    if (tid == 0) lastf = (atomicAdd(&cnt1[b], 1u) == 7u) ? 1u : 0u;
    __syncthreads();
    if (!lastf) return;
    __threadfence();
    if (tid == 0) {
        const float mS = __int_as_float(atomicMax((int*)&amax1[b * 2 + 0], 0));
        const float mP = __int_as_float(atomicMax((int*)&amax1[b * 2 + 1], 0));
        // mem during any seg <= maxP + maxS/(1-0.9^64); margin covers fp error
        dirtyf = !((mP + mS * 1.0012f) * 1.0001f <= 0.999f) ? 1u : 0u;
    }
    __syncthreads();
    if (!dirtyf) {
        if (tid < 64) rowany1[b * 64 + tid] = 0u;
        return;
    }
    // ---- cold: exact serial replay (256 threads) ----
    float* buf = pool;               // 16 KB reuse
    const int ig = tid >> 5;         // membranes i = ig*4..+4
    const int wavei = tid >> 6;
    float mem[4] = {0.f, 0.f, 0.f, 0.f};
    unsigned int u[4] = {0u, 0u, 0u, 0u};
    for (int c = 0; c < 8; ++c) {
        __syncthreads();
        #pragma unroll
        for (int r = 0; r < 4; ++r) {
            const int s4 = tid + 256 * r;
            const int dt = s4 >> 4, q = s4 & 15;
            *(float4*)&buf[dt * 64 + q * 4] =
                *(const float4*)(kvq1 + ((size_t)b * T_STEPS + c * 64 + dt) * KVQ + q * 4);
        }
        __syncthreads();
        for (int dt = 0; dt < 64; ++dt) {
            const float4 kk = *(const float4*)&buf[dt * 64 + ig * 4];
            const float vv = buf[dt * 64 + 32 + j];
            const float kf[4] = {kk.x, kk.y, kk.z, kk.w};
            #pragma unroll
            for (int r = 0; r < 4; ++r) {
                mem[r] = fmaf(0.9f, mem[r], kf[r] * vv);
                const bool s = mem[r] > 1.f; if (s) mem[r] -= 1.f;
                u[r] |= (s ? 1u : 0u) << (dt & 31);
            }
            if ((dt & 31) == 31) {
                const int wg = c * 2 + (dt >> 5);
                unsigned int* dm = dmask1 + (size_t)(wg * 64 + b) * 1024;
                unsigned int a = 0;
                #pragma unroll
                for (int r = 0; r < 4; ++r) {
                    dm[(ig * 4 + r) * 32 + j] = u[r];
                    a |= u[r]; u[r] = 0u;
                }
                #pragma unroll
                for (int off = 32; off; off >>= 1) a |= __shfl_xor(a, off);
                if ((tid & 63) == 0) rowany1[(b * 4 + wavei) * 16 + wg] = a;
            }
        }
    }
}

// ---------------------------------------------------------------- mid + cert/cleanup (layer 2)
// grid 512 = b*8+seg, block 128.
__global__ __launch_bounds__(128) void midc_kernel(
    const unsigned int* __restrict__ rowany1, const unsigned int* __restrict__ dmask1,
    const float* __restrict__ kvq1,
    const float* __restrict__ W_mid, const float* __restrict__ b_mid,
    const float* __restrict__ Wk2, const float* __restrict__ bk2,
    const float* __restrict__ Wv2, const float* __restrict__ bv2,
    const float* __restrict__ Wq2, const float* __restrict__ bq2,
    const float* __restrict__ const2, float* __restrict__ kvq2,
    unsigned int* __restrict__ rowany2, unsigned int* __restrict__ dmask2,
    unsigned int* __restrict__ cnt2, float* __restrict__ amax2)
{
    const int b = blockIdx.x >> 3, seg = blockIdx.x & 7;
    const int tid = threadIdx.x;
    const int w0 = seg * 2;
    const float G64 = 9.988209815422261f;       // (1-0.9^64)/0.1
    __shared__ __align__(16) float c2s[KVQ];
    __shared__ __align__(16) float kt2[64 * 64];   // 16 KB (k,v); reused as buf
    __shared__ float h2[HID];
    __shared__ unsigned int msk[NN];
    __shared__ float red[4];
    __shared__ unsigned int lastf, dirtyf;
    if (tid < KVQ) c2s[tid] = const2[tid];
    __syncthreads();
    const unsigned int orA = rowany1[(b * 4 + 0) * 16 + w0] | rowany1[(b * 4 + 1) * 16 + w0]
                           | rowany1[(b * 4 + 2) * 16 + w0] | rowany1[(b * 4 + 3) * 16 + w0];
    const unsigned int orB = rowany1[(b * 4 + 0) * 16 + w0 + 1] | rowany1[(b * 4 + 1) * 16 + w0 + 1]
                           | rowany1[(b * 4 + 2) * 16 + w0 + 1] | rowany1[(b * 4 + 3) * 16 + w0 + 1];
    if ((orA | orB) != 0u) {
        // ---- mixed (cold): exact rows + tile phase1 ----
        float* obase = kvq2 + ((size_t)b * T_STEPS + seg * 64) * KVQ;
        for (int d = 0; d < 64; ++d) {
            const unsigned int orw = (d < 32) ? orA : orB;
            const int bit = d & 31;
            if (!((orw >> bit) & 1u)) {
                if (tid < 16) *(float4*)&kt2[d * 64 + tid * 4] = ((const float4*)c2s)[tid];
            } else {
                const int wg = w0 + (d >> 5);
                const unsigned int* dmw = dmask1 + (size_t)(wg * 64 + b) * 1024;
                for (int i2 = 0; i2 < NN; i2 += 4) {
                    const int i = i2 + (tid >> 5);
                    const unsigned int wb = dmw[i * 32 + (tid & 31)];
                    const unsigned long long balm = __ballot(((wb >> bit) & 1u) != 0);
                    const int ibase = i2 + (tid >> 6) * 2;
                    if ((tid & 63) == 0)  msk[ibase]     = (unsigned int)balm;
                    if ((tid & 63) == 32) msk[ibase + 1] = (unsigned int)(balm >> 32);
                }
                for (int cc = tid; cc < HID; cc += 128) h2[cc] = b_mid[cc];
                __syncthreads();
                const float* qrow = kvq1 + ((size_t)b * T_STEPS + seg * 64 + d) * KVQ + 2 * NN;
                for (int i = 0; i < NN; ++i) {
                    unsigned int m = msk[i];
                    if (!m) continue;
                    const float qv = qrow[i];
                    while (m) {
                        const int jj = __ffs(m) - 1; m &= m - 1;
                        const float* wr = W_mid + (size_t)(i * NN + jj) * HID;
                        for (int cc = tid; cc < HID; cc += 128)
                            h2[cc] = fmaf(qv, wr[cc], h2[cc]);
                    }
                }
                __syncthreads();
                for (int cc = tid; cc < HID; cc += 128) h2[cc] = fmaxf(h2[cc], 0.f);
                __syncthreads();
                if (tid < KVQ) {
                    const int sel = tid >> 5, nn = tid & 31;
                    const float* W2 = sel == 0 ? Wk2 : sel == 1 ? Wv2 : Wq2;
                    float a2 = (sel == 0 ? bk2 : sel == 1 ? bv2 : bq2)[nn];
                    for (int cc = 0; cc < HID; ++cc)
                        a2 = fmaf(h2[cc], W2[cc * NN + nn], a2);
                    if (sel == 2) a2 = sigmoidf_(a2);
                    obase[d * KVQ + tid] = a2;
                    if (tid < 64) kt2[d * 64 + tid] = a2;
                }
                __syncthreads();
            }
        }
        __syncthreads();
        const int i0 = (tid >> 5) * 8, j = tid & 31;
        float p[8], am[8];
        #pragma unroll
        for (int r = 0; r < 8; ++r) { p[r] = 0.f; am[r] = 0.f; }
        for (int tt = 0; tt < 16; ++tt) {
            float4 k0[4], k1[4]; float vv[4];
            #pragma unroll
            for (int d2 = 0; d2 < 4; ++d2) {
                const int t = tt * 4 + d2;
                k0[d2] = *(const float4*)&kt2[t * 64 + i0];
                k1[d2] = *(const float4*)&kt2[t * 64 + i0 + 4];
                vv[d2] = kt2[t * 64 + 32 + j];
            }
            #pragma unroll
            for (int d2 = 0; d2 < 4; ++d2) {
                const float kf[8] = {k0[d2].x, k0[d2].y, k0[d2].z, k0[d2].w,
                                     k1[d2].x, k1[d2].y, k1[d2].z, k1[d2].w};
                #pragma unroll
                for (int r = 0; r < 8; ++r) {
                    p[r] = fmaf(0.9f, p[r], kf[r] * vv[d2]);
                    am[r] = fmaxf(am[r], fabsf(p[r]));
                }
            }
        }
        float ls = 0.f, lp = 0.f;
        #pragma unroll
        for (int r = 0; r < 8; ++r) { ls = fmaxf(ls, fabsf(p[r])); lp = fmaxf(lp, am[r]); }
        #pragma unroll
        for (int off = 32; off; off >>= 1) {
            ls = fmaxf(ls, __shfl_xor(ls, off));
            lp = fmaxf(lp, __shfl_xor(lp, off));
        }
        if ((tid & 63) == 0) { red[(tid >> 6) * 2] = ls; red[(tid >> 6) * 2 + 1] = lp; }
        __syncthreads();
        if (tid == 0) {
            atomicMax((int*)&amax2[b * 2 + 0], __float_as_int(fmaxf(red[0], red[2])));
            atomicMax((int*)&amax2[b * 2 + 1], __float_as_int(fmaxf(red[1], red[3])));
        }
    }
    // ---- last-block handoff ----
    __threadfence();
    __syncthreads();
    if (tid == 0) lastf = (atomicAdd(&cnt2[b], 1u) == 7u) ? 1u : 0u;
    __syncthreads();
    if (!lastf) return;
    __threadfence();
    if (tid == 0) {
        float mk = 0.f, mv = 0.f;
        #pragma unroll 8
        for (int i = 0; i < 32; ++i) {
            mk = fmaxf(mk, fabsf(c2s[i]));
            mv = fmaxf(mv, fabsf(c2s[32 + i]));
        }
        const float scs = mk * mv * G64;   // closed-form bound for clean segs
        const float mS = fmaxf(__int_as_float(atomicMax((int*)&amax2[b * 2 + 0], 0)), scs);
        const float mP = fmaxf(__int_as_float(atomicMax((int*)&amax2[b * 2 + 1], 0)), scs);
        dirtyf = !((mP + mS * 1.0012f) * 1.0001f <= 0.999f) ? 1u : 0u;
    }
    __syncthreads();
    if (!dirtyf) {
        if (tid < 64) rowany2[b * 64 + tid] = 0u;
        return;
    }
    // ---- cold: exact serial replay (128 threads, 8 membranes/thread),
    //      const2 row substitution for layer-1-clean t ----
    float* buf = kt2;
    const int j = tid & 31, ig = tid >> 5;   // i = ig*8..+8, iq = ig
    float mem[8]; unsigned int u[8];
    #pragma unroll
    for (int r = 0; r < 8; ++r) { mem[r] = 0.f; u[r] = 0u; }
    for (int c = 0; c < 8; ++c) {
        unsigned int oA = 0u, oB = 0u;
        #pragma unroll
        for (int iq = 0; iq < 4; ++iq) {
            oA |= rowany1[(b * 4 + iq) * 16 + 2 * c];
            oB |= rowany1[(b * 4 + iq) * 16 + 2 * c + 1];
        }
        __syncthreads();
        #pragma unroll
        for (int r = 0; r < 8; ++r) {
            const int s4 = tid + 128 * r;
            const int dt = s4 >> 4, q = s4 & 15;
            const unsigned int orw = (dt < 32) ? oA : oB;
            float4 val;
            if (!((orw >> (dt & 31)) & 1u))
                val = *(const float4*)&c2s[q * 4];
            else
                val = *(const float4*)(kvq2 + ((size_t)b * T_STEPS + c * 64 + dt) * KVQ + q * 4);
            *(float4*)&buf[dt * 64 + q * 4] = val;
        }
        __syncthreads();
        for (int dt = 0; dt < 64; ++dt) {
            const float4 ka = *(const float4*)&buf[dt * 64 + ig * 8];
            const float4 kb2 = *(const float4*)&buf[dt * 64 + ig * 8 + 4];
            const float vv = buf[dt * 64 + 32 + j];
            const float kf[8] = {ka.x, ka.y, ka.z, ka.w, kb2.x, kb2.y, kb2.z, kb2.w};
            #pragma unroll
            for (int r = 0; r < 8; ++r) {
                mem[r] = fmaf(0.9f, mem[r], kf[r] * vv);
                const bool s = mem[r] > 1.f; if (s) mem[r] -= 1.f;
                u[r] |= (s ? 1u : 0u) << (dt & 31);
            }
            if ((dt & 31) == 31) {
                const int wg = c * 2 + (dt >> 5);
                unsigned int* dm = dmask2 + (size_t)(wg * 64 + b) * 1024;
                unsigned int a = 0;
                #pragma unroll
                for (int r = 0; r < 8; ++r) {
                    dm[(ig * 8 + r) * 32 + j] = u[r];
                    a |= u[r]; u[r] = 0u;
                }
                #pragma unroll
                for (int off = 16; off; off >>= 1) a |= __shfl_xor(a, off);
                if ((tid & 31) == 0) rowany2[(b * 4 + ig) * 16 + wg] = a;
            }
        }
    }
}

// ---------------------------------------------------------------- out
__global__ __launch_bounds__(256) void out_kernel(
    const unsigned int* __restrict__ rowany2, const unsigned int* __restrict__ dmask2,
    const unsigned int* __restrict__ rowany1,
    const float* __restrict__ kvq2, const float* __restrict__ const2,
    const float* __restrict__ W_out, const float* __restrict__ b_out,
    float* __restrict__ y)
{
    const int blk = blockIdx.x;
    const int b = blk >> 2, tq = blk & 3;
    const int tid = threadIdx.x;
    const int wave = tid >> 6, lane = tid & 63;
    const int wg = tq * 4 + wave;
    __shared__ unsigned int mskws[4][NN];
    const int g16 = lane & 15;
    const float4 bo = ((const float4*)b_out)[g16];
    const float4 sy = make_float4(sigmoidf_(bo.x), sigmoidf_(bo.y),
                                  sigmoidf_(bo.z), sigmoidf_(bo.w));
    const unsigned int or4 = rowany2[(b * 4 + 0) * 16 + wg]
                           | rowany2[(b * 4 + 1) * 16 + wg]
                           | rowany2[(b * 4 + 2) * 16 + wg]
                           | rowany2[(b * 4 + 3) * 16 + wg];
    if (or4 == 0) {
        #pragma unroll
        for (int d = 0; d < 32; d += 4) {
            const int t = wg * 32 + d + (lane >> 4);
            ((float4*)(y + ((size_t)t * 64 + b) * OUTW))[g16] = sy;
        }
        return;
    }
    const unsigned int or1 = rowany1[(b * 4 + 0) * 16 + wg]
                           | rowany1[(b * 4 + 1) * 16 + wg]
                           | rowany1[(b * 4 + 2) * 16 + wg]
                           | rowany1[(b * 4 + 3) * 16 + wg];
    for (int d = 0; d < 32; ++d) {
        const int t = wg * 32 + d;
        float* yr = y + ((size_t)t * 64 + b) * OUTW;
        if (!((or4 >> d) & 1u)) {
            if (lane < 16) ((float4*)yr)[lane] = sy;
            continue;
        }
        const unsigned int* dmw = dmask2 + (size_t)(wg * 64 + b) * 1024;
        for (int i2 = 0; i2 < NN; i2 += 2) {
            const int i = i2 + (lane >> 5), jj = lane & 31;
            const unsigned int wbits = dmw[i * 32 + jj];
            const unsigned long long bal = __ballot(((wbits >> d) & 1u) != 0);
            if (lane == 0)  mskws[wave][i2] = (unsigned int)bal;
            if (lane == 32) mskws[wave][i2 + 1] = (unsigned int)(bal >> 32);
        }
        const float* qrow = ((or1 >> d) & 1u)
            ? kvq2 + ((size_t)b * T_STEPS + t) * KVQ + 2 * NN
            : const2 + 2 * NN;
        float a = b_out[lane];
        for (int i = 0; i < NN; ++i) {
            unsigned int m = mskws[wave][i];
            if (!m) continue;
            const float qv = qrow[i];
            while (m) {
                const int jj = __ffs(m) - 1; m &= m - 1;
                a = fmaf(qv, W_out[(size_t)(i * NN + jj) * OUTW + lane], a);
            }
        }
        yr[lane] = sigmoidf_(a);
    }
}

// ---------------------------------------------------------------- launch
extern "C" void kernel_launch(void* const* d_in, const int* in_sizes, int n_in,
                              void* d_out, int out_size, void* d_ws, size_t ws_size,
                              hipStream_t stream)
{
    const float* x     = (const float*)d_in[0];
    const float* W_in  = (const float*)d_in[1];
    const float* b_in  = (const float*)d_in[2];
    const float* Wk1   = (const float*)d_in[3];
    const float* bk1   = (const float*)d_in[4];
    const float* Wv1   = (const float*)d_in[5];
    const float* bv1   = (const float*)d_in[6];
    const float* Wq1   = (const float*)d_in[7];
    const float* bq1   = (const float*)d_in[8];
    const float* W_mid = (const float*)d_in[9];
    const float* b_mid = (const float*)d_in[10];
    const float* Wk2   = (const float*)d_in[11];
    const float* bk2   = (const float*)d_in[12];
    const float* Wv2   = (const float*)d_in[13];
    const float* bv2   = (const float*)d_in[14];
    const float* Wq2   = (const float*)d_in[15];
    const float* bq2   = (const float*)d_in[16];
    const float* W_out = (const float*)d_in[17];
    const float* b_out = (const float*)d_in[18];
    float* y = (float*)d_out;

    float* ws = (float*)d_ws;
    float* W1eff  = ws;                                 // 6240
    float* b1eff  = ws + 6240;
    float* const2 = ws + 6336;                          // pad to 8192
    float* kvq1   = ws + 8192;                          // 3,145,728 (b-major)
    float* kvq2   = kvq1 + 3145728;                     // 3,145,728 (b-major)
    unsigned int* dmask1  = (unsigned int*)(kvq2 + 3145728);   // 1,048,576
    unsigned int* dmask2  = dmask1 + 1048576;                  // 1,048,576
    unsigned int* rowany1 = dmask2 + 1048576;                  // 4096
    unsigned int* rowany2 = rowany1 + 4096;                    // 4096
    unsigned int* ctrl    = rowany2 + 4096;                    // 384
    unsigned int* cnt1  = ctrl;                // 64
    unsigned int* cnt2  = ctrl + 64;           // 64
    float* amax1 = (float*)(ctrl + 128);       // 128
    float* amax2 = (float*)(ctrl + 256);       // 128

    prep_kernel<<<INW + 2, 512, 0, stream>>>(W_in, b_in, Wk1, bk1, Wv1, bv1, Wq1, bq1,
                                             b_mid, Wk2, bk2, Wv2, bv2, Wq2, bq2,
                                             W1eff, b1eff, const2, ctrl);
    kvq1p1c_kernel<<<BATCH * 8, 256, 0, stream>>>(x, W1eff, b1eff, kvq1,
                                                  rowany1, dmask1, cnt1, amax1);
    midc_kernel<<<BATCH * 8, 128, 0, stream>>>(rowany1, dmask1, kvq1, W_mid, b_mid,
                                               Wk2, bk2, Wv2, bv2, Wq2, bq2,
                                               const2, kvq2, rowany2, dmask2,
                                               cnt2, amax2);
    out_kernel<<<BATCH * 4, 256, 0, stream>>>(rowany2, dmask2, rowany1,
                                              kvq2, const2, W_out, b_out, y);
}

// Round 11
// 144.007 us; speedup vs baseline: 1.5039x; 1.5039x over previous
//
#include <hip/hip_runtime.h>
#include <math.h>

// Gen2AssocModel forward. T=512, B=64, N=32, HID=1024, SEQ_WIDTH=64.
// R11 = exact revert to R9 (best measured: 141.0 us). R10's fence-based
// single-kernel fusion regressed to 216 us (device-scope __threadfence x512
// blocks serializes L2 drains). 7 dispatches:
//   prep:    W1eff = W_in @ [Wk1|Wv1|Wq1] (65x96), b1eff, const2.
//   kvq1:    (32768x65)@(65x96), 4row x 12col register tiles, float4 LDS.
//   phase1:  per (b,seg=64t): 16KB staged k|v, 4 membranes/thread, register
//            double-buffer; cert1[b,seg] = (max|S|, max P) scalars.
//   cc:      per b: scalar cert chain; clean -> rowany=0; dirty -> EXACT
//            serial replay (const2 row substitution on layer 2).
//   mid:     clean seg -> return; mixed -> exact dirty rows + tile phase1.
//   out:     rowany2 fast path -> sigmoid(b_out); sparse cold exact.
// Workspace ~32 MB.

#define T_STEPS 512
#define BATCH   64
#define NN      32
#define HID     1024
#define INW     65
#define OUTW    64
#define ROWS    (T_STEPS * BATCH)
#define KVQ     96

__device__ __forceinline__ float sigmoidf_(float x) { return 1.0f / (1.0f + expf(-x)); }

// ---------------------------------------------------------------- prep
__global__ __launch_bounds__(512) void prep_kernel(
    const float* __restrict__ W_in, const float* __restrict__ b_in,
    const float* __restrict__ Wk1, const float* __restrict__ bk1,
    const float* __restrict__ Wv1, const float* __restrict__ bv1,
    const float* __restrict__ Wq1, const float* __restrict__ bq1,
    const float* __restrict__ b_mid,
    const float* __restrict__ Wk2, const float* __restrict__ bk2,
    const float* __restrict__ Wv2, const float* __restrict__ bv2,
    const float* __restrict__ Wq2, const float* __restrict__ bq2,
    float* __restrict__ W1eff, float* __restrict__ b1eff,
    float* __restrict__ const2)
{
    const int m = blockIdx.x;                 // 0..66
    const int tid = threadIdx.x;
    __shared__ float srcv[HID];
    __shared__ float part[512];
    for (int h = tid; h < HID; h += 512) {
        float s;
        if (m < INW)       s = W_in[m * HID + h];
        else if (m == INW) s = b_in[h];
        else               s = fmaxf(b_mid[h], 0.f);
        srcv[h] = s;
    }
    __syncthreads();
    const int hq = tid >> 7, ns = tid & 127;  // ns<96 active
    const int sel = ns >> 5, nn = ns & 31;
    const bool layer2 = (m == INW + 1);
    const float* W = layer2 ? (sel == 0 ? Wk2 : sel == 1 ? Wv2 : Wq2)
                            : (sel == 0 ? Wk1 : sel == 1 ? Wv1 : Wq1);
    float acc = 0.f;
    if (ns < KVQ) {
        const int h0 = hq * 256;
        #pragma unroll 8
        for (int hh = 0; hh < 256; ++hh)
            acc = fmaf(srcv[h0 + hh], W[(h0 + hh) * NN + nn], acc);
    }
    part[tid] = acc;
    __syncthreads();
    if (hq == 0 && ns < KVQ) {
        float tot = part[ns] + part[128 + ns] + part[256 + ns] + part[384 + ns];
        if (m < INW) {
            W1eff[m * KVQ + ns] = tot;
        } else if (m == INW) {
            tot += (sel == 0 ? bk1 : sel == 1 ? bv1 : bq1)[nn];
            b1eff[ns] = tot;
        } else {
            tot += (sel == 0 ? bk2 : sel == 1 ? bv2 : bq2)[nn];
            const2[ns] = (sel == 2) ? sigmoidf_(tot) : tot;
        }
    }
}

// ---------------------------------------------------------------- kvq1 (R4 shape, known-good)
// grid 256, block 256. 128 rows/block; thread = 4 rows x 12 cols.
__global__ __launch_bounds__(256) void kvq1_kernel(
    const float* __restrict__ x, const float* __restrict__ W1eff,
    const float* __restrict__ b1eff, float* __restrict__ kvq1)
{
    const int tid = threadIdx.x;
    const int r0 = blockIdx.x * 128;
    __shared__ float Ws[INW * KVQ];        // 24.4 KB
    __shared__ float xsT[INW * 132];       // 34.3 KB  [m][row], pad 132
    __shared__ float bs[KVQ];
    for (int i4 = tid; i4 < (INW * KVQ) / 4; i4 += 256)
        ((float4*)Ws)[i4] = ((const float4*)W1eff)[i4];
    for (int l = tid; l < 128 * INW; l += 256) {
        const int r = l / INW, m = l - r * INW;
        xsT[m * 132 + r] = x[(size_t)(r0 + r) * INW + m];
    }
    if (tid < KVQ) bs[tid] = b1eff[tid];
    __syncthreads();
    const int rg = tid >> 3;          // 0..31 -> rows rg*4..+3
    const int c0 = (tid & 7) * 12;    // cols [c0, c0+12)
    float acc[4][12];
    #pragma unroll
    for (int r = 0; r < 4; ++r)
        #pragma unroll
        for (int k = 0; k < 12; ++k) acc[r][k] = bs[c0 + k];
    for (int m = 0; m < INW; ++m) {
        const float4 xv = *(const float4*)&xsT[m * 132 + rg * 4];
        const float4 w0 = *(const float4*)&Ws[m * KVQ + c0];
        const float4 w1 = *(const float4*)&Ws[m * KVQ + c0 + 4];
        const float4 w2 = *(const float4*)&Ws[m * KVQ + c0 + 8];
        const float xr[4] = {xv.x, xv.y, xv.z, xv.w};
        const float wk[12] = {w0.x, w0.y, w0.z, w0.w, w1.x, w1.y, w1.z, w1.w,
                              w2.x, w2.y, w2.z, w2.w};
        #pragma unroll
        for (int r = 0; r < 4; ++r)
            #pragma unroll
            for (int k = 0; k < 12; ++k)
                acc[r][k] = fmaf(xr[r], wk[k], acc[r][k]);
    }
    #pragma unroll
    for (int r = 0; r < 4; ++r) {
        const int g = r0 + rg * 4 + r;   // = t*64 + b
        const int t = g >> 6, b = g & 63;
        float* o = kvq1 + ((size_t)b * T_STEPS + t) * KVQ + c0;
        float v[12];
        #pragma unroll
        for (int k = 0; k < 12; ++k)
            v[k] = (c0 + k >= 2 * NN) ? sigmoidf_(acc[r][k]) : acc[r][k];
        *(float4*)&o[0] = make_float4(v[0], v[1], v[2], v[3]);
        *(float4*)&o[4] = make_float4(v[4], v[5], v[6], v[7]);
        *(float4*)&o[8] = make_float4(v[8], v[9], v[10], v[11]);
    }
}

// ---------------------------------------------------------------- phase1 (standalone)
// grid 512 = b*8+seg, block 256 (4 waves), 16 KB LDS. 4 membranes/thread
// (i0 = (tid>>5)*4, j = tid&31), register double-buffered 4-step batches.
// Emits cert[(b*8+seg)*2] = max|S|, [..+1] = max P.
__global__ __launch_bounds__(256) void phase1_kernel(
    const float* __restrict__ kvq, float* __restrict__ cert)
{
    const int b = blockIdx.x >> 3, seg = blockIdx.x & 7;
    const int tid = threadIdx.x;
    __shared__ __align__(16) float buf[64 * 64];   // 16 KB: [dt][k(32)|v(32)]
    __shared__ float red[8];
    const float* base = kvq + ((size_t)b * T_STEPS + seg * 64) * KVQ;
    #pragma unroll
    for (int r = 0; r < 4; ++r) {
        const int l4 = tid + 256 * r;          // 0..1023
        const int dt = l4 >> 4, q = l4 & 15;   // cols 0..63 = k|v
        *(float4*)&buf[dt * 64 + q * 4] = *(const float4*)(base + dt * KVQ + q * 4);
    }
    __syncthreads();
    const int i0 = (tid >> 5) * 4, j = tid & 31;
    float p[4] = {0.f, 0.f, 0.f, 0.f};
    float am[4] = {0.f, 0.f, 0.f, 0.f};
    float4 kb[2][4]; float vb[2][4];
    #pragma unroll
    for (int d = 0; d < 4; ++d) {
        kb[0][d] = *(const float4*)&buf[d * 64 + i0];
        vb[0][d] = buf[d * 64 + 32 + j];
    }
    #pragma unroll
    for (int bt = 0; bt < 16; ++bt) {
        const int cb = bt & 1;
        if (bt < 15) {
            #pragma unroll
            for (int d = 0; d < 4; ++d) {
                const int dt = (bt + 1) * 4 + d;
                kb[cb ^ 1][d] = *(const float4*)&buf[dt * 64 + i0];
                vb[cb ^ 1][d] = buf[dt * 64 + 32 + j];
            }
        }
        #pragma unroll
        for (int d = 0; d < 4; ++d) {
            const float vv = vb[cb][d];
            p[0] = fmaf(0.9f, p[0], kb[cb][d].x * vv); am[0] = fmaxf(am[0], fabsf(p[0]));
            p[1] = fmaf(0.9f, p[1], kb[cb][d].y * vv); am[1] = fmaxf(am[1], fabsf(p[1]));
            p[2] = fmaf(0.9f, p[2], kb[cb][d].z * vv); am[2] = fmaxf(am[2], fabsf(p[2]));
            p[3] = fmaf(0.9f, p[3], kb[cb][d].w * vv); am[3] = fmaxf(am[3], fabsf(p[3]));
        }
    }
    float ls = 0.f, lp = 0.f;
    #pragma unroll
    for (int r = 0; r < 4; ++r) { ls = fmaxf(ls, fabsf(p[r])); lp = fmaxf(lp, am[r]); }
    #pragma unroll
    for (int off = 32; off; off >>= 1) {
        ls = fmaxf(ls, __shfl_xor(ls, off));
        lp = fmaxf(lp, __shfl_xor(lp, off));
    }
    const int lane = tid & 63, wv = tid >> 6;
    if (lane == 0) { red[wv * 2] = ls; red[wv * 2 + 1] = lp; }
    __syncthreads();
    if (tid == 0) {
        cert[blockIdx.x * 2 + 0] = fmaxf(fmaxf(red[0], red[2]), fmaxf(red[4], red[6]));
        cert[blockIdx.x * 2 + 1] = fmaxf(fmaxf(red[1], red[3]), fmaxf(red[5], red[7]));
    }
}

// ---------------------------------------------------------------- cc (cert + cleanup)
__global__ __launch_bounds__(256) void cc_kernel(
    const float* __restrict__ cert, const float* __restrict__ kvq,
    unsigned int* __restrict__ rowany, unsigned int* __restrict__ dmask,
    const unsigned int* __restrict__ rowany_prev, const float* __restrict__ cdef)
{
    const int b = blockIdx.x;
    const int tid = threadIdx.x;
    const float c64 = 0.0011790184577738599f;   // 0.9^64
    const float G64 = 9.988209815422261f;       // (1-0.9^64)/0.1
    __shared__ __align__(16) float c2l[64];
    float scs = 0.f;
    if (cdef) {
        if (tid < 64) c2l[tid] = cdef[tid];
        __syncthreads();
        float mk = 0.f, mv = 0.f;
        #pragma unroll 8
        for (int i = 0; i < 32; ++i) {
            mk = fmaxf(mk, fabsf(c2l[i]));
            mv = fmaxf(mv, fabsf(c2l[32 + i]));
        }
        scs = mk * mv * G64;
    }
    float Mb = 0.f;
    bool fl = false;
    #pragma unroll
    for (int g = 0; g < 8; ++g) {
        bool mixed = true;
        if (rowany_prev) {
            unsigned int m = 0u;
            #pragma unroll
            for (int iq = 0; iq < 4; ++iq)
                m |= rowany_prev[(b * 4 + iq) * 16 + 2 * g]
                   | rowany_prev[(b * 4 + iq) * 16 + 2 * g + 1];
            mixed = (m != 0u);
        }
        float smax, pmax;
        if (mixed) { smax = cert[(b * 8 + g) * 2]; pmax = cert[(b * 8 + g) * 2 + 1]; }
        else       { smax = scs; pmax = scs; }
        const float ub = Mb + pmax;              // Mb >= 0 by construction
        fl |= !(ub * 1.0001f <= 0.999f);
        Mb = fmaf(c64, Mb, smax);
    }
    if (!fl) {
        if (tid < 64) rowany[b * 64 + tid] = 0u;
        return;
    }
    // ---- cold: exact serial replay ----
    __shared__ float buf[64 * 64];   // 16 KB: [dt][k(32)|v(32)]
    const int j = tid & 31, ig = tid >> 5;   // membranes i = ig*4..+4
    const int wavei = tid >> 6;
    float mem[4] = {0.f, 0.f, 0.f, 0.f};
    unsigned int u[4] = {0u, 0u, 0u, 0u};
    for (int c = 0; c < 8; ++c) {
        unsigned int orA = 0xFFFFFFFFu, orB = 0xFFFFFFFFu;
        if (rowany_prev) {
            orA = 0u; orB = 0u;
            #pragma unroll
            for (int iq = 0; iq < 4; ++iq) {
                orA |= rowany_prev[(b * 4 + iq) * 16 + 2 * c];
                orB |= rowany_prev[(b * 4 + iq) * 16 + 2 * c + 1];
            }
        }
        __syncthreads();
        #pragma unroll
        for (int r = 0; r < 4; ++r) {
            const int s4 = tid + 256 * r;          // 1024 float4 slots
            const int dt = s4 >> 4, q = s4 & 15;   // cols 0..63 = k|v
            const unsigned int orw = (dt < 32) ? orA : orB;
            float4 val;
            if (rowany_prev && !((orw >> (dt & 31)) & 1u))
                val = *(const float4*)&c2l[q * 4];
            else
                val = *(const float4*)(kvq + ((size_t)b * T_STEPS + c * 64 + dt) * KVQ + q * 4);
            *(float4*)&buf[dt * 64 + q * 4] = val;
        }
        __syncthreads();
        for (int dt = 0; dt < 64; ++dt) {
            const float4 kk = *(const float4*)&buf[dt * 64 + ig * 4];
            const float vv = buf[dt * 64 + 32 + j];
            const float kf[4] = {kk.x, kk.y, kk.z, kk.w};
            #pragma unroll
            for (int r = 0; r < 4; ++r) {
                mem[r] = fmaf(0.9f, mem[r], kf[r] * vv);
                const bool s = mem[r] > 1.f; if (s) mem[r] -= 1.f;
                u[r] |= (s ? 1u : 0u) << (dt & 31);
            }
            if ((dt & 31) == 31) {
                const int wg = c * 2 + (dt >> 5);
                unsigned int* dm = dmask + (size_t)(wg * 64 + b) * 1024;
                unsigned int a = 0;
                #pragma unroll
                for (int r = 0; r < 4; ++r) {
                    dm[(ig * 4 + r) * 32 + j] = u[r];
                    a |= u[r]; u[r] = 0u;
                }
                #pragma unroll
                for (int off = 32; off; off >>= 1) a |= __shfl_xor(a, off);
                if ((tid & 63) == 0) rowany[(b * 4 + wavei) * 16 + wg] = a;
            }
        }
    }
}

// ---------------------------------------------------------------- mid (sparse only)
__global__ __launch_bounds__(128) void mid_kernel(
    const unsigned int* __restrict__ rowany1, const unsigned int* __restrict__ dmask1,
    const float* __restrict__ kvq1,
    const float* __restrict__ W_mid, const float* __restrict__ b_mid,
    const float* __restrict__ Wk2, const float* __restrict__ bk2,
    const float* __restrict__ Wv2, const float* __restrict__ bv2,
    const float* __restrict__ Wq2, const float* __restrict__ bq2,
    const float* __restrict__ const2, float* __restrict__ kvq2,
    float* __restrict__ cert2)
{
    const int b = blockIdx.x >> 3, seg = blockIdx.x & 7;
    const int tid = threadIdx.x;
    const int w0 = seg * 2;
    const unsigned int orA = rowany1[(b * 4 + 0) * 16 + w0] | rowany1[(b * 4 + 1) * 16 + w0]
                           | rowany1[(b * 4 + 2) * 16 + w0] | rowany1[(b * 4 + 3) * 16 + w0];
    const unsigned int orB = rowany1[(b * 4 + 0) * 16 + w0 + 1] | rowany1[(b * 4 + 1) * 16 + w0 + 1]
                           | rowany1[(b * 4 + 2) * 16 + w0 + 1] | rowany1[(b * 4 + 3) * 16 + w0 + 1];
    if ((orA | orB) == 0u) return;
    // ---- mixed (cold) ----
    __shared__ __align__(16) float c2s[KVQ];
    __shared__ __align__(16) float kt2[64 * 64];   // 16 KB (k,v)
    __shared__ float h2[HID];
    __shared__ unsigned int msk[NN];
    __shared__ float red[4];
    if (tid < KVQ) c2s[tid] = const2[tid];
    __syncthreads();
    float* obase = kvq2 + ((size_t)b * T_STEPS + seg * 64) * KVQ;
    for (int d = 0; d < 64; ++d) {
        const unsigned int orw = (d < 32) ? orA : orB;
        const int bit = d & 31;
        if (!((orw >> bit) & 1u)) {
            if (tid < 16) *(float4*)&kt2[d * 64 + tid * 4] = ((const float4*)c2s)[tid];
        } else {
            const int wg = w0 + (d >> 5);
            const unsigned int* dmw = dmask1 + (size_t)(wg * 64 + b) * 1024;
            for (int i2 = 0; i2 < NN; i2 += 4) {
                const int i = i2 + (tid >> 5);
                const unsigned int wb = dmw[i * 32 + (tid & 31)];
                const unsigned long long balm = __ballot(((wb >> bit) & 1u) != 0);
                const int ibase = i2 + (tid >> 6) * 2;
                if ((tid & 63) == 0)  msk[ibase]     = (unsigned int)balm;
                if ((tid & 63) == 32) msk[ibase + 1] = (unsigned int)(balm >> 32);
            }
            for (int cc = tid; cc < HID; cc += 128) h2[cc] = b_mid[cc];
            __syncthreads();
            const float* qrow = kvq1 + ((size_t)b * T_STEPS + seg * 64 + d) * KVQ + 2 * NN;
            for (int i = 0; i < NN; ++i) {
                unsigned int m = msk[i];
                if (!m) continue;
                const float qv = qrow[i];
                while (m) {
                    const int jj = __ffs(m) - 1; m &= m - 1;
                    const float* wr = W_mid + (size_t)(i * NN + jj) * HID;
                    for (int cc = tid; cc < HID; cc += 128)
                        h2[cc] = fmaf(qv, wr[cc], h2[cc]);
                }
            }
            __syncthreads();
            for (int cc = tid; cc < HID; cc += 128) h2[cc] = fmaxf(h2[cc], 0.f);
            __syncthreads();
            if (tid < KVQ) {
                const int sel = tid >> 5, nn = tid & 31;
                const float* W2 = sel == 0 ? Wk2 : sel == 1 ? Wv2 : Wq2;
                float a2 = (sel == 0 ? bk2 : sel == 1 ? bv2 : bq2)[nn];
                for (int cc = 0; cc < HID; ++cc)
                    a2 = fmaf(h2[cc], W2[cc * NN + nn], a2);
                if (sel == 2) a2 = sigmoidf_(a2);
                obase[d * KVQ + tid] = a2;
                if (tid < 64) kt2[d * 64 + tid] = a2;
            }
            __syncthreads();
        }
    }
    __syncthreads();
    const int i0 = (tid >> 5) * 8, j = tid & 31;
    float p[8], am[8];
    #pragma unroll
    for (int r = 0; r < 8; ++r) { p[r] = 0.f; am[r] = 0.f; }
    for (int tt = 0; tt < 16; ++tt) {
        float4 k0[4], k1[4]; float vv[4];
        #pragma unroll
        for (int d2 = 0; d2 < 4; ++d2) {
            const int t = tt * 4 + d2;
            k0[d2] = *(const float4*)&kt2[t * 64 + i0];
            k1[d2] = *(const float4*)&kt2[t * 64 + i0 + 4];
            vv[d2] = kt2[t * 64 + 32 + j];
        }
        #pragma unroll
        for (int d2 = 0; d2 < 4; ++d2) {
            const float kf[8] = {k0[d2].x, k0[d2].y, k0[d2].z, k0[d2].w,
                                 k1[d2].x, k1[d2].y, k1[d2].z, k1[d2].w};
            #pragma unroll
            for (int r = 0; r < 8; ++r) {
                p[r] = fmaf(0.9f, p[r], kf[r] * vv[d2]);
                am[r] = fmaxf(am[r], fabsf(p[r]));
            }
        }
    }
    float ls = 0.f, lp = 0.f;
    #pragma unroll
    for (int r = 0; r < 8; ++r) { ls = fmaxf(ls, fabsf(p[r])); lp = fmaxf(lp, am[r]); }
    #pragma unroll
    for (int off = 32; off; off >>= 1) {
        ls = fmaxf(ls, __shfl_xor(ls, off));
        lp = fmaxf(lp, __shfl_xor(lp, off));
    }
    const int lane = tid & 63, wv = tid >> 6;
    if (lane == 0) { red[wv * 2] = ls; red[wv * 2 + 1] = lp; }
    __syncthreads();
    if (tid == 0) {
        cert2[blockIdx.x * 2 + 0] = fmaxf(red[0], red[2]);
        cert2[blockIdx.x * 2 + 1] = fmaxf(red[1], red[3]);
    }
}

// ---------------------------------------------------------------- out
__global__ __launch_bounds__(256) void out_kernel(
    const unsigned int* __restrict__ rowany2, const unsigned int* __restrict__ dmask2,
    const unsigned int* __restrict__ rowany1,
    const float* __restrict__ kvq2, const float* __restrict__ const2,
    const float* __restrict__ W_out, const float* __restrict__ b_out,
    float* __restrict__ y)
{
    const int blk = blockIdx.x;
    const int b = blk >> 2, tq = blk & 3;
    const int tid = threadIdx.x;
    const int wave = tid >> 6, lane = tid & 63;
    const int wg = tq * 4 + wave;
    __shared__ unsigned int mskws[4][NN];
    const int g16 = lane & 15;
    const float4 bo = ((const float4*)b_out)[g16];
    const float4 sy = make_float4(sigmoidf_(bo.x), sigmoidf_(bo.y),
                                  sigmoidf_(bo.z), sigmoidf_(bo.w));
    const unsigned int or4 = rowany2[(b * 4 + 0) * 16 + wg]
                           | rowany2[(b * 4 + 1) * 16 + wg]
                           | rowany2[(b * 4 + 2) * 16 + wg]
                           | rowany2[(b * 4 + 3) * 16 + wg];
    if (or4 == 0) {
        #pragma unroll
        for (int d = 0; d < 32; d += 4) {
            const int t = wg * 32 + d + (lane >> 4);
            ((float4*)(y + ((size_t)t * 64 + b) * OUTW))[g16] = sy;
        }
        return;
    }
    const unsigned int or1 = rowany1[(b * 4 + 0) * 16 + wg]
                           | rowany1[(b * 4 + 1) * 16 + wg]
                           | rowany1[(b * 4 + 2) * 16 + wg]
                           | rowany1[(b * 4 + 3) * 16 + wg];
    for (int d = 0; d < 32; ++d) {
        const int t = wg * 32 + d;
        float* yr = y + ((size_t)t * 64 + b) * OUTW;
        if (!((or4 >> d) & 1u)) {
            if (lane < 16) ((float4*)yr)[lane] = sy;
            continue;
        }
        const unsigned int* dmw = dmask2 + (size_t)(wg * 64 + b) * 1024;
        for (int i2 = 0; i2 < NN; i2 += 2) {
            const int i = i2 + (lane >> 5), jj = lane & 31;
            const unsigned int wbits = dmw[i * 32 + jj];
            const unsigned long long bal = __ballot(((wbits >> d) & 1u) != 0);
            if (lane == 0)  mskws[wave][i2] = (unsigned int)bal;
            if (lane == 32) mskws[wave][i2 + 1] = (unsigned int)(bal >> 32);
        }
        const float* qrow = ((or1 >> d) & 1u)
            ? kvq2 + ((size_t)b * T_STEPS + t) * KVQ + 2 * NN
            : const2 + 2 * NN;
        float a = b_out[lane];
        for (int i = 0; i < NN; ++i) {
            unsigned int m = mskws[wave][i];
            if (!m) continue;
            const float qv = qrow[i];
            while (m) {
                const int jj = __ffs(m) - 1; m &= m - 1;
                a = fmaf(qv, W_out[(size_t)(i * NN + jj) * OUTW + lane], a);
            }
        }
        yr[lane] = sigmoidf_(a);
    }
}

// ---------------------------------------------------------------- launch
extern "C" void kernel_launch(void* const* d_in, const int* in_sizes, int n_in,
                              void* d_out, int out_size, void* d_ws, size_t ws_size,
                              hipStream_t stream)
{
    const float* x     = (const float*)d_in[0];
    const float* W_in  = (const float*)d_in[1];
    const float* b_in  = (const float*)d_in[2];
    const float* Wk1   = (const float*)d_in[3];
    const float* bk1   = (const float*)d_in[4];
    const float* Wv1   = (const float*)d_in[5];
    const float* bv1   = (const float*)d_in[6];
    const float* Wq1   = (const float*)d_in[7];
    const float* bq1   = (const float*)d_in[8];
    const float* W_mid = (const float*)d_in[9];
    const float* b_mid = (const float*)d_in[10];
    const float* Wk2   = (const float*)d_in[11];
    const float* bk2   = (const float*)d_in[12];
    const float* Wv2   = (const float*)d_in[13];
    const float* bv2   = (const float*)d_in[14];
    const float* Wq2   = (const float*)d_in[15];
    const float* bq2   = (const float*)d_in[16];
    const float* W_out = (const float*)d_in[17];
    const float* b_out = (const float*)d_in[18];
    float* y = (float*)d_out;

    float* ws = (float*)d_ws;
    float* W1eff  = ws;                                 // 6240
    float* b1eff  = ws + 6240;
    float* const2 = ws + 6336;                          // pad to 8192
    float* kvq1   = ws + 8192;                          // 3,145,728 (b-major)
    float* kvq2   = kvq1 + 3145728;                     // 3,145,728 (b-major)
    unsigned int* dmask1  = (unsigned int*)(kvq2 + 3145728);   // 1,048,576
    unsigned int* dmask2  = dmask1 + 1048576;                  // 1,048,576
    unsigned int* rowany1 = dmask2 + 1048576;                  // 4096
    unsigned int* rowany2 = rowany1 + 4096;                    // 4096
    float* cert1 = (float*)(rowany2 + 4096);            // 1024
    float* cert2 = cert1 + 1024;                        // 1024

    prep_kernel<<<INW + 2, 512, 0, stream>>>(W_in, b_in, Wk1, bk1, Wv1, bv1, Wq1, bq1,
                                             b_mid, Wk2, bk2, Wv2, bv2, Wq2, bq2,
                                             W1eff, b1eff, const2);
    kvq1_kernel<<<ROWS / 128, 256, 0, stream>>>(x, W1eff, b1eff, kvq1);
    phase1_kernel<<<BATCH * 8, 256, 0, stream>>>(kvq1, cert1);
    cc_kernel<<<BATCH, 256, 0, stream>>>(cert1, kvq1, rowany1, dmask1,
                                         (const unsigned int*)nullptr,
                                         (const float*)nullptr);
    mid_kernel<<<BATCH * 8, 128, 0, stream>>>(rowany1, dmask1, kvq1, W_mid, b_mid,
                                              Wk2, bk2, Wv2, bv2, Wq2, bq2,
                                              const2, kvq2, cert2);
    cc_kernel<<<BATCH, 256, 0, stream>>>(cert2, kvq2, rowany2, dmask2,
                                         rowany1, const2);
    out_kernel<<<BATCH * 4, 256, 0, stream>>>(rowany2, dmask2, rowany1,
                                              kvq2, const2, W_out, b_out, y);
}